// Round 6
// baseline (4105.491 us; speedup 1.0000x reference)
//
#include <hip/hip_runtime.h>
#include <math.h>

#define B_ 8
#define T_ 32
#define N_ 10000
#define F_ 16
#define E_ 160000
#define HG_ 64
#define HT_ 128
#define BT_ (B_*T_)
#define PB_ 157   // ceil(N/64) node-chunks per bt
#define EPS_ 1e-5f

__device__ inline float4 shfl_xor4(float4 v, int m) {
  float4 r;
  r.x = __shfl_xor(v.x, m); r.y = __shfl_xor(v.y, m);
  r.z = __shfl_xor(v.z, m); r.w = __shfl_xor(v.w, m);
  return r;
}

// fp32 -> bf16 bits, round-to-nearest-even
__device__ inline unsigned short f2bf(float f) {
  unsigned u = __float_as_uint(f);
  u += 0x7fffu + ((u >> 16) & 1u);
  return (unsigned short)(u >> 16);
}
__device__ inline float bflo(unsigned u) { return __uint_as_float(u << 16); }
__device__ inline float bfhi(unsigned u) { return __uint_as_float(u & 0xffff0000u); }
// accumulate 4 bf16 (packed in uint2) into float4
__device__ inline void accb(float4& a, uint2 v) {
  a.x += bflo(v.x); a.y += bfhi(v.x);
  a.z += bflo(v.y); a.w += bfhi(v.y);
}

// ---------------- CSR build ----------------
__global__ void k_zero(int* p, int n) {
  int i = blockIdx.x * 256 + threadIdx.x;
  if (i < n) p[i] = 0;
}

__global__ void k_deg(const int* __restrict__ dst, int* __restrict__ deg) {
  int e = blockIdx.x * 256 + threadIdx.x;
  if (e < E_) atomicAdd(&deg[dst[e]], 1);
}

__global__ void k_scan(const int* __restrict__ deg, int* __restrict__ row_ptr,
                       float* __restrict__ inv_deg) {
  __shared__ int part[256];
  int tid = threadIdx.x;
  int base = tid * 40;
  int s = 0;
  for (int i = 0; i < 40; i++) { int idx = base + i; if (idx < N_) s += deg[idx]; }
  part[tid] = s;
  __syncthreads();
  if (tid == 0) {
    int run = 0;
    for (int i = 0; i < 256; i++) { int v = part[i]; part[i] = run; run += v; }
  }
  __syncthreads();
  int run = part[tid];
  for (int i = 0; i < 40; i++) {
    int idx = base + i;
    if (idx < N_) {
      row_ptr[idx] = run;
      int d = deg[idx];
      run += d;
      inv_deg[idx] = 1.0f / fmaxf((float)d, 1.0f);
    } else if (idx == N_) {
      row_ptr[N_] = run;
    }
  }
}

__global__ void k_fill(const int* __restrict__ src, const int* __restrict__ dst,
                       const int* __restrict__ row_ptr, int* __restrict__ cursor,
                       int* __restrict__ col) {
  int e = blockIdx.x * 256 + threadIdx.x;
  if (e < E_) {
    int d = dst[e];
    int p = atomicAdd(&cursor[d], 1);
    col[row_ptr[d] + p] = src[e];
  }
}

// ---------------- weight transpose for sage2 phase B ----------------
__global__ void k_prepw(const float* __restrict__ W2l, const float* __restrict__ W2r,
                        float* __restrict__ Wt) {
  int idx = blockIdx.x * 256 + threadIdx.x;   // 8192 total
  if (idx >= 4 * 128 * 16) return;
  int w = idx >> 11;
  int r = idx & 2047;
  int k = r >> 4;
  int jj = r & 15;
  int j = w * 16 + jj;
  float v = (k < 64) ? W2l[j * 64 + k] : W2r[j * 64 + (k - 64)];
  Wt[idx] = v;
}

// ---------------- SAGE layer 1 (F=16 -> HG=64), quad-node gather, bf16 out ----
// 4 independent waves (wave-private LDS, no block barriers). 8 blocks/CU.
__launch_bounds__(256, 8)
__global__ void k_sage1(const float* __restrict__ x, const int* __restrict__ row_ptr,
                        const int* __restrict__ col, const float* __restrict__ inv_deg,
                        const float* __restrict__ W1l, const float* __restrict__ b1,
                        const float* __restrict__ W1r, const float* __restrict__ g1,
                        const float* __restrict__ be1, unsigned short* __restrict__ h1,
                        int bt0, int CH, int swz) {
  __shared__ float aggQ[4][4][16];
  __shared__ float selfQ[4][4][16];
  __shared__ __align__(16) unsigned short hstage[4][4][64];   // wave x node x feat
  int i = blockIdx.x;
  int btl, chunk;
  if (swz) {  // pin all blocks of one bt to one XCD
    int xcd = i & 7; int j = i >> 3; int per = CH >> 3;
    btl = xcd * per + j / PB_; chunk = j % PB_;
  } else {
    btl = i / PB_; chunk = i % PB_;
  }
  int bt = bt0 + btl;
  size_t xbase = (size_t)bt * (N_ * F_);
  int tid = threadIdx.x, wave = tid >> 6, lane = tid & 63;
  int f = lane & 15, eo = lane >> 4;

  float4 wl[4], wr[4];
  const float4* Wl4 = (const float4*)(W1l + lane * 16);
  const float4* Wr4 = (const float4*)(W1r + lane * 16);
#pragma unroll
  for (int q = 0; q < 4; q++) { wl[q] = Wl4[q]; wr[q] = Wr4[q]; }
  float bj = b1[lane], gj = g1[lane], bej = be1[lane];

  for (int p = 0; p < 16; p += 4) {
    int nA = chunk * 64 + wave * 16 + p;
    int nB = nA + 1, nC = nA + 2, nD = nA + 3;
    bool okA = nA < N_, okB = nB < N_, okC = nC < N_, okD = nD < N_;
    int s0A = 0, dA = 0, s0B = 0, dB = 0, s0C = 0, dC = 0, s0D = 0, dD = 0;
    float ivA = 0.f, ivB = 0.f, ivC = 0.f, ivD = 0.f;
    if (okA) { s0A = row_ptr[nA]; dA = row_ptr[nA + 1] - s0A; ivA = inv_deg[nA]; }
    if (okB) { s0B = row_ptr[nB]; dB = row_ptr[nB + 1] - s0B; ivB = inv_deg[nB]; }
    if (okC) { s0C = row_ptr[nC]; dC = row_ptr[nC + 1] - s0C; ivC = inv_deg[nC]; }
    if (okD) { s0D = row_ptr[nD]; dD = row_ptr[nD + 1] - s0D; ivD = inv_deg[nD]; }
    int colA = (lane < dA) ? col[s0A + lane] : 0;
    int colB = (lane < dB) ? col[s0B + lane] : 0;
    int colC = (lane < dC) ? col[s0C + lane] : 0;
    int colD = (lane < dD) ? col[s0D + lane] : 0;
    int dcA = dA > 64 ? 64 : dA, dcB = dB > 64 ? 64 : dB;
    int dcC = dC > 64 ? 64 : dC, dcD = dD > 64 ? 64 : dD;
    int mx = max(max(dcA, dcB), max(dcC, dcD));
    float aA = 0.f, aB = 0.f, aC = 0.f, aD = 0.f;
    int rounds = (mx + 3) >> 2;
    for (int r = 0; r < rounds; ++r) {
      int idx = eo + 4 * r;     // <= 63
      int sA = __shfl(colA, idx), sB = __shfl(colB, idx);
      int sC = __shfl(colC, idx), sD = __shfl(colD, idx);
      if (idx < dcA) aA += x[xbase + (size_t)sA * F_ + f];
      if (idx < dcB) aB += x[xbase + (size_t)sB * F_ + f];
      if (idx < dcC) aC += x[xbase + (size_t)sC * F_ + f];
      if (idx < dcD) aD += x[xbase + (size_t)sD * F_ + f];
    }
    if (dA > 64) for (int e = s0A + 64; e < s0A + dA; ++e) { if (eo == 0) aA += x[xbase + (size_t)col[e] * F_ + f]; }
    if (dB > 64) for (int e = s0B + 64; e < s0B + dB; ++e) { if (eo == 0) aB += x[xbase + (size_t)col[e] * F_ + f]; }
    if (dC > 64) for (int e = s0C + 64; e < s0C + dC; ++e) { if (eo == 0) aC += x[xbase + (size_t)col[e] * F_ + f]; }
    if (dD > 64) for (int e = s0D + 64; e < s0D + dD; ++e) { if (eo == 0) aD += x[xbase + (size_t)col[e] * F_ + f]; }
    aA += __shfl_xor(aA, 16); aA += __shfl_xor(aA, 32);
    aB += __shfl_xor(aB, 16); aB += __shfl_xor(aB, 32);
    aC += __shfl_xor(aC, 16); aC += __shfl_xor(aC, 32);
    aD += __shfl_xor(aD, 16); aD += __shfl_xor(aD, 32);
    float asel = (eo == 0) ? aA * ivA : (eo == 1) ? aB * ivB : (eo == 2) ? aC * ivC : aD * ivD;
    int nS = nA + eo;
    float xsel = (nS < N_) ? x[xbase + (size_t)nS * F_ + f] : 0.f;
    aggQ[wave][eo][f] = asel;
    selfQ[wave][eo][f] = xsel;
    __builtin_amdgcn_wave_barrier();
    float h0 = bj, h1v = bj, h2 = bj, h3 = bj;
    const float4* a40 = (const float4*)aggQ[wave][0];
    const float4* a41 = (const float4*)aggQ[wave][1];
    const float4* a42 = (const float4*)aggQ[wave][2];
    const float4* a43 = (const float4*)aggQ[wave][3];
    const float4* s40 = (const float4*)selfQ[wave][0];
    const float4* s41 = (const float4*)selfQ[wave][1];
    const float4* s42 = (const float4*)selfQ[wave][2];
    const float4* s43 = (const float4*)selfQ[wave][3];
#pragma unroll
    for (int q = 0; q < 4; q++) {
      float4 v0 = a40[q], v1 = a41[q], v2 = a42[q], v3 = a43[q];
      h0 = fmaf(v0.x, wl[q].x, h0); h1v = fmaf(v1.x, wl[q].x, h1v); h2 = fmaf(v2.x, wl[q].x, h2); h3 = fmaf(v3.x, wl[q].x, h3);
      h0 = fmaf(v0.y, wl[q].y, h0); h1v = fmaf(v1.y, wl[q].y, h1v); h2 = fmaf(v2.y, wl[q].y, h2); h3 = fmaf(v3.y, wl[q].y, h3);
      h0 = fmaf(v0.z, wl[q].z, h0); h1v = fmaf(v1.z, wl[q].z, h1v); h2 = fmaf(v2.z, wl[q].z, h2); h3 = fmaf(v3.z, wl[q].z, h3);
      h0 = fmaf(v0.w, wl[q].w, h0); h1v = fmaf(v1.w, wl[q].w, h1v); h2 = fmaf(v2.w, wl[q].w, h2); h3 = fmaf(v3.w, wl[q].w, h3);
      float4 u0 = s40[q], u1 = s41[q], u2 = s42[q], u3 = s43[q];
      h0 = fmaf(u0.x, wr[q].x, h0); h1v = fmaf(u1.x, wr[q].x, h1v); h2 = fmaf(u2.x, wr[q].x, h2); h3 = fmaf(u3.x, wr[q].x, h3);
      h0 = fmaf(u0.y, wr[q].y, h0); h1v = fmaf(u1.y, wr[q].y, h1v); h2 = fmaf(u2.y, wr[q].y, h2); h3 = fmaf(u3.y, wr[q].y, h3);
      h0 = fmaf(u0.z, wr[q].z, h0); h1v = fmaf(u1.z, wr[q].z, h1v); h2 = fmaf(u2.z, wr[q].z, h2); h3 = fmaf(u3.z, wr[q].z, h3);
      h0 = fmaf(u0.w, wr[q].w, h0); h1v = fmaf(u1.w, wr[q].w, h1v); h2 = fmaf(u2.w, wr[q].w, h2); h3 = fmaf(u3.w, wr[q].w, h3);
    }
    __builtin_amdgcn_wave_barrier();
    float t0 = h0, t1 = h1v, t2 = h2, t3 = h3;
#pragma unroll
    for (int m = 1; m < 64; m <<= 1) {
      t0 += __shfl_xor(t0, m); t1 += __shfl_xor(t1, m);
      t2 += __shfl_xor(t2, m); t3 += __shfl_xor(t3, m);
    }
    float d0 = h0 - t0 * (1.f / 64.f), d1 = h1v - t1 * (1.f / 64.f);
    float d2 = h2 - t2 * (1.f / 64.f), d3 = h3 - t3 * (1.f / 64.f);
    float v0 = d0 * d0, v1 = d1 * d1, v2 = d2 * d2, v3 = d3 * d3;
#pragma unroll
    for (int m = 1; m < 64; m <<= 1) {
      v0 += __shfl_xor(v0, m); v1 += __shfl_xor(v1, m);
      v2 += __shfl_xor(v2, m); v3 += __shfl_xor(v3, m);
    }
    float r0 = rsqrtf(v0 * (1.f / 64.f) + EPS_), r1 = rsqrtf(v1 * (1.f / 64.f) + EPS_);
    float r2 = rsqrtf(v2 * (1.f / 64.f) + EPS_), r3 = rsqrtf(v3 * (1.f / 64.f) + EPS_);
    // stage 4 bf16 rows in LDS, then ONE dword2 store per lane (512B/wave,
    // dword-granular, stays in L2/L3 for sage2t -- no nt, no sub-word RMW)
    hstage[wave][0][lane] = f2bf(fmaxf(d0 * r0 * gj + bej, 0.f));
    hstage[wave][1][lane] = f2bf(fmaxf(d1 * r1 * gj + bej, 0.f));
    hstage[wave][2][lane] = f2bf(fmaxf(d2 * r2 * gj + bej, 0.f));
    hstage[wave][3][lane] = f2bf(fmaxf(d3 * r3 * gj + bej, 0.f));
    __builtin_amdgcn_wave_barrier();
    int q = lane >> 4, fo = lane & 15;
    uint2 pv = *(const uint2*)&hstage[wave][q][fo * 4];
    int nq = nA + q;
    if (nq < N_) *(uint2*)(h1 + ((size_t)btl * N_ + nq) * HG_ + fo * 4) = pv;
    __builtin_amdgcn_wave_barrier();
  }
}

// ---------------- SAGE layer 2 (bf16 in), tiled; bf16 Z tile, 8 blocks/CU ----
__launch_bounds__(256, 8)
__global__ void k_sage2t(const unsigned short* __restrict__ h1, const int* __restrict__ row_ptr,
                         const int* __restrict__ col, const float* __restrict__ inv_deg,
                         const float* __restrict__ Wt, const float* __restrict__ b2,
                         const float* __restrict__ g2, const float* __restrict__ be2,
                         float* __restrict__ Hsum, int bt0, int CH, int swz) {
  __shared__ __align__(16) unsigned short Zb[64 * 132];   // 16.9 KB (bf16)
  __shared__ float red[2][4][64];
  __shared__ float sw[64];
  int i = blockIdx.x;
  int btl, chunk;
  if (swz) {
    int xcd = i & 7; int j = i >> 3; int per = CH >> 3;
    btl = xcd * per + j / PB_; chunk = j % PB_;
  } else {
    btl = i / PB_; chunk = i % PB_;
  }
  int bt = bt0 + btl;
  int b = bt / T_, t = bt % T_;
  size_t hbase = (size_t)btl * (N_ * HG_);
  const uint2* h4 = (const uint2*)(h1 + hbase);   // one row = 16 uint2 (64 bf16)
  int tid = threadIdx.x;
  int w = __builtin_amdgcn_readfirstlane(tid >> 6);
  int lane = tid & 63;
  int n0 = chunk * 64;
  int eo = lane >> 4, fq = lane & 15;

  // ---- Phase A: quads of nodes, 8B bf16x4 gathers ----
  for (int p = 0; p < 16; p += 4) {
    int mA = w * 16 + p;
    int nA = n0 + mA, nB = nA + 1, nC = nA + 2, nD = nA + 3;
    bool okA = nA < N_, okB = nB < N_, okC = nC < N_, okD = nD < N_;
    int s0A = 0, dA = 0, s0B = 0, dB = 0, s0C = 0, dC = 0, s0D = 0, dD = 0;
    float ivA = 0.f, ivB = 0.f, ivC = 0.f, ivD = 0.f;
    if (okA) { s0A = row_ptr[nA]; dA = row_ptr[nA + 1] - s0A; ivA = inv_deg[nA]; }
    if (okB) { s0B = row_ptr[nB]; dB = row_ptr[nB + 1] - s0B; ivB = inv_deg[nB]; }
    if (okC) { s0C = row_ptr[nC]; dC = row_ptr[nC + 1] - s0C; ivC = inv_deg[nC]; }
    if (okD) { s0D = row_ptr[nD]; dD = row_ptr[nD + 1] - s0D; ivD = inv_deg[nD]; }
    int colA = (lane < dA) ? col[s0A + lane] : 0;
    int colB = (lane < dB) ? col[s0B + lane] : 0;
    int colC = (lane < dC) ? col[s0C + lane] : 0;
    int colD = (lane < dD) ? col[s0D + lane] : 0;
    int dcA = dA > 64 ? 64 : dA, dcB = dB > 64 ? 64 : dB;
    int dcC = dC > 64 ? 64 : dC, dcD = dD > 64 ? 64 : dD;
    int mx = max(max(dcA, dcB), max(dcC, dcD));
    float4 aA = {0, 0, 0, 0}, aB = {0, 0, 0, 0}, aC = {0, 0, 0, 0}, aD = {0, 0, 0, 0};
    int rounds = (mx + 3) >> 2;
    for (int r = 0; r < rounds; ++r) {
      int idx = eo + 4 * r;    // <= 63
      int sA = __shfl(colA, idx), sB = __shfl(colB, idx);
      int sC = __shfl(colC, idx), sD = __shfl(colD, idx);
      if (idx < dcA) accb(aA, h4[(size_t)sA * 16 + fq]);
      if (idx < dcB) accb(aB, h4[(size_t)sB * 16 + fq]);
      if (idx < dcC) accb(aC, h4[(size_t)sC * 16 + fq]);
      if (idx < dcD) accb(aD, h4[(size_t)sD * 16 + fq]);
    }
    if (dA > 64) for (int e = s0A + 64; e < s0A + dA; ++e) { if (eo == 0) accb(aA, h4[(size_t)col[e] * 16 + fq]); }
    if (dB > 64) for (int e = s0B + 64; e < s0B + dB; ++e) { if (eo == 0) accb(aB, h4[(size_t)col[e] * 16 + fq]); }
    if (dC > 64) for (int e = s0C + 64; e < s0C + dC; ++e) { if (eo == 0) accb(aC, h4[(size_t)col[e] * 16 + fq]); }
    if (dD > 64) for (int e = s0D + 64; e < s0D + dD; ++e) { if (eo == 0) accb(aD, h4[(size_t)col[e] * 16 + fq]); }
    float4 tA = shfl_xor4(aA, 16); aA.x += tA.x; aA.y += tA.y; aA.z += tA.z; aA.w += tA.w;
    tA = shfl_xor4(aA, 32); aA.x += tA.x; aA.y += tA.y; aA.z += tA.z; aA.w += tA.w;
    float4 tB = shfl_xor4(aB, 16); aB.x += tB.x; aB.y += tB.y; aB.z += tB.z; aB.w += tB.w;
    tB = shfl_xor4(aB, 32); aB.x += tB.x; aB.y += tB.y; aB.z += tB.z; aB.w += tB.w;
    float4 tC = shfl_xor4(aC, 16); aC.x += tC.x; aC.y += tC.y; aC.z += tC.z; aC.w += tC.w;
    tC = shfl_xor4(aC, 32); aC.x += tC.x; aC.y += tC.y; aC.z += tC.z; aC.w += tC.w;
    float4 tD = shfl_xor4(aD, 16); aD.x += tD.x; aD.y += tD.y; aD.z += tD.z; aD.w += tD.w;
    tD = shfl_xor4(aD, 32); aD.x += tD.x; aD.y += tD.y; aD.z += tD.z; aD.w += tD.w;
    float iv = (eo == 0) ? ivA : (eo == 1) ? ivB : (eo == 2) ? ivC : ivD;
    float4 agg = (eo == 0) ? aA : (eo == 1) ? aB : (eo == 2) ? aC : aD;
    agg.x *= iv; agg.y *= iv; agg.z *= iv; agg.w *= iv;
    uint2 ap;
    ap.x = (unsigned)f2bf(agg.x) | ((unsigned)f2bf(agg.y) << 16);
    ap.y = (unsigned)f2bf(agg.z) | ((unsigned)f2bf(agg.w) << 16);
    *(uint2*)&Zb[(mA + eo) * 132 + fq * 4] = ap;
    int nS = nA + eo;
    uint2 sv = {0, 0};
    if (nS < N_) sv = h4[(size_t)nS * 16 + fq];
    *(uint2*)&Zb[(mA + eo) * 132 + 64 + fq * 4] = sv;
  }
  __syncthreads();

  // ---- Phase B: lane = node m; wave-uniform scalar weight loads ----
  int m = lane;
  const float* wp0 = Wt + w * 2048;
  float acc[16];
#pragma unroll
  for (int jj = 0; jj < 16; ++jj) acc[jj] = b2[w * 16 + jj];
  const unsigned short* zrow = Zb + m * 132;
  for (int kg = 0; kg < 32; ++kg) {
    uint2 zp = *(const uint2*)(zrow + kg * 4);
    float4 z;
    z.x = bflo(zp.x); z.y = bfhi(zp.x);
    z.z = bflo(zp.y); z.w = bfhi(zp.y);
    const float* wp = wp0 + kg * 64;
#pragma unroll
    for (int jj = 0; jj < 16; ++jj) {
      acc[jj] = fmaf(z.x, wp[jj], acc[jj]);
      acc[jj] = fmaf(z.y, wp[16 + jj], acc[jj]);
      acc[jj] = fmaf(z.z, wp[32 + jj], acc[jj]);
      acc[jj] = fmaf(z.w, wp[48 + jj], acc[jj]);
    }
  }

  // ---- LayerNorm across j (4 waves hold j-quarters) ----
  float s1 = 0.f;
#pragma unroll
  for (int jj = 0; jj < 16; ++jj) s1 += acc[jj];
  red[0][w][m] = s1;
  __syncthreads();
  float mu = (red[0][0][m] + red[0][1][m] + red[0][2][m] + red[0][3][m]) * (1.f / 64.f);
  float v = 0.f;
#pragma unroll
  for (int jj = 0; jj < 16; ++jj) { float d = acc[jj] - mu; v += d * d; }
  red[1][w][m] = v;
  __syncthreads();
  float var = (red[1][0][m] + red[1][1][m] + red[1][2][m] + red[1][3][m]) * (1.f / 64.f);
  float r = rsqrtf(var + EPS_);

  // ---- relu + mean-over-N partial ----
  bool okm = (n0 + m) < N_;
#pragma unroll
  for (int jj = 0; jj < 16; ++jj) {
    float hv = fmaxf((acc[jj] - mu) * r * g2[w * 16 + jj] + be2[w * 16 + jj], 0.f);
    acc[jj] = okm ? hv : 0.f;
  }
#pragma unroll
  for (int m2 = 1; m2 < 64; m2 <<= 1) {
#pragma unroll
    for (int jj = 0; jj < 16; ++jj) acc[jj] += __shfl_xor(acc[jj], m2);
  }
  if (lane == 0) {
#pragma unroll
    for (int jj = 0; jj < 16; ++jj) sw[w * 16 + jj] = acc[jj];
  }
  __syncthreads();
  if (w == 0) atomicAdd(&Hsum[(t * B_ + b) * HG_ + lane], sw[lane]);
}

// ---------------- GRU input precompute: GI[t][b][384] ----------------
__global__ void k_gi(const float* __restrict__ Hsum, const float* __restrict__ W_ih,
                     const float* __restrict__ b_ih, float* __restrict__ GI) {
  __shared__ float xv[64];
  int tb = blockIdx.x;
  int tid = threadIdx.x;
  if (tid < 64) xv[tid] = Hsum[tb * 64 + tid] * (1.0f / (float)N_);
  __syncthreads();
  float g = b_ih[tid];
  const float4* W4 = (const float4*)(W_ih + tid * 64);
  const float4* x4 = (const float4*)xv;
#pragma unroll
  for (int q = 0; q < 16; q++) {
    float4 w = W4[q], xq = x4[q];
    g = fmaf(xq.x, w.x, g); g = fmaf(xq.y, w.y, g);
    g = fmaf(xq.z, w.z, g); g = fmaf(xq.w, w.w, g);
  }
  GI[tb * 384 + tid] = g;
}

// ---------------- sequential GRU + head; one block per batch ----------------
__global__ void k_gru(const float* __restrict__ GI, const float* __restrict__ W_hh,
                      const float* __restrict__ b_hh, const float* __restrict__ Wh,
                      const float* __restrict__ bh, float* __restrict__ out) {
  __shared__ float hL[128];
  __shared__ float ghL[384];
  __shared__ float red[128];
  int b = blockIdx.x, tid = threadIdx.x;
  if (tid < 128) hL[tid] = 0.f;
  float bhh = b_hh[tid];
  const float4* W4 = (const float4*)(W_hh + tid * 128);
  for (int t = 0; t < T_; ++t) {
    __syncthreads();
    float g = bhh;
    const float4* h4 = (const float4*)hL;
#pragma unroll
    for (int q = 0; q < 32; q++) {
      float4 w = W4[q], hv = h4[q];
      g = fmaf(hv.x, w.x, g); g = fmaf(hv.y, w.y, g);
      g = fmaf(hv.z, w.z, g); g = fmaf(hv.w, w.w, g);
    }
    ghL[tid] = g;
    __syncthreads();
    float hnew = 0.f;
    if (tid < 128) {
      const float* gi = GI + (t * B_ + b) * 384;
      float rr = 1.f / (1.f + expf(-(gi[tid] + ghL[tid])));
      float zz = 1.f / (1.f + expf(-(gi[128 + tid] + ghL[128 + tid])));
      float nn = tanhf(gi[256 + tid] + rr * ghL[256 + tid]);
      hnew = (1.f - zz) * nn + zz * hL[tid];
    }
    __syncthreads();
    if (tid < 128) hL[tid] = hnew;
  }
  __syncthreads();
  if (tid < 128) red[tid] = hL[tid] * Wh[tid];
  __syncthreads();
  if (tid == 0) {
    float s = bh[0];
    for (int k = 0; k < 128; k++) s += red[k];
    out[b] = s;
  }
}

extern "C" void kernel_launch(void* const* d_in, const int* in_sizes, int n_in,
                              void* d_out, int out_size, void* d_ws, size_t ws_size,
                              hipStream_t stream) {
  const float* x    = (const float*)d_in[0];
  const int*   ei   = (const int*)d_in[1];
  const float* W1l  = (const float*)d_in[2];
  const float* b1   = (const float*)d_in[3];
  const float* W1r  = (const float*)d_in[4];
  const float* g1   = (const float*)d_in[5];
  const float* be1  = (const float*)d_in[6];
  const float* W2l  = (const float*)d_in[7];
  const float* b2   = (const float*)d_in[8];
  const float* W2r  = (const float*)d_in[9];
  const float* g2   = (const float*)d_in[10];
  const float* be2  = (const float*)d_in[11];
  const float* W_ih = (const float*)d_in[12];
  const float* W_hh = (const float*)d_in[13];
  const float* b_ih = (const float*)d_in[14];
  const float* b_hh = (const float*)d_in[15];
  const float* Wh   = (const float*)d_in[16];
  const float* bh   = (const float*)d_in[17];
  float* out = (float*)d_out;

  char* ws = (char*)d_ws;
  size_t off = 0;
  auto alloc = [&](size_t bytes) { void* p = ws + off; off += (bytes + 255) & ~(size_t)255; return p; };
  int*   deg     = (int*)alloc((size_t)N_ * 4);
  int*   row_ptr = (int*)alloc((size_t)(N_ + 1) * 4);
  int*   cursor  = (int*)alloc((size_t)N_ * 4);
  int*   col     = (int*)alloc((size_t)E_ * 4);
  float* ivd     = (float*)alloc((size_t)N_ * 4);
  float* Hsum    = (float*)alloc((size_t)BT_ * HG_ * 4);
  float* GI      = (float*)alloc((size_t)BT_ * 384 * 4);
  float* Wt      = (float*)alloc((size_t)4 * 128 * 16 * 4);
  size_t fixed = off;
  unsigned short* h1 = (unsigned short*)(ws + off);

  size_t cap = (ws_size > fixed) ? (ws_size - fixed) : 0;
  int CH = (int)(cap / ((size_t)N_ * HG_ * 2));   // bf16 h1
  if (CH > 64) CH = 64;    // keep chunk working set inside the 256MB L3
  if (CH >= 8) CH &= ~7;   // multiple of 8 for XCD swizzle
  if (CH < 1) CH = 1;

  int zn = (int)(fixed / 4);
  k_zero<<<(zn + 255) / 256, 256, 0, stream>>>((int*)ws, zn);

  const int* srcp = ei;
  const int* dstp = ei + E_;
  k_deg<<<(E_ + 255) / 256, 256, 0, stream>>>(dstp, deg);
  k_scan<<<1, 256, 0, stream>>>(deg, row_ptr, ivd);
  k_fill<<<(E_ + 255) / 256, 256, 0, stream>>>(srcp, dstp, row_ptr, cursor, col);
  k_prepw<<<32, 256, 0, stream>>>(W2l, W2r, Wt);

  for (int bt0 = 0; bt0 < BT_; bt0 += CH) {
    int c = BT_ - bt0 < CH ? BT_ - bt0 : CH;
    int swz = (c % 8 == 0) ? 1 : 0;
    k_sage1<<<c * PB_, 256, 0, stream>>>(x, row_ptr, col, ivd, W1l, b1, W1r, g1, be1,
                                         h1, bt0, c, swz);
    k_sage2t<<<c * PB_, 256, 0, stream>>>(h1, row_ptr, col, ivd, Wt, b2, g2, be2,
                                          Hsum, bt0, c, swz);
  }
  k_gi<<<BT_, 384, 0, stream>>>(Hsum, W_ih, b_ih, GI);
  k_gru<<<B_, 384, 0, stream>>>(GI, W_hh, b_hh, Wh, bh, out);
}

// Round 7
// 1964.506 us; speedup vs baseline: 2.0898x; 2.0898x over previous
//
#include <hip/hip_runtime.h>
#include <math.h>

#define B_ 8
#define T_ 32
#define N_ 10000
#define F_ 16
#define E_ 160000
#define HG_ 64
#define HT_ 128
#define BT_ (B_*T_)
#define PB_ 157   // ceil(N/64) node-chunks per bt
#define EPS_ 1e-5f

__device__ inline float4 shfl_xor4(float4 v, int m) {
  float4 r;
  r.x = __shfl_xor(v.x, m); r.y = __shfl_xor(v.y, m);
  r.z = __shfl_xor(v.z, m); r.w = __shfl_xor(v.w, m);
  return r;
}

// fp32 -> bf16 bits, round-to-nearest-even
__device__ inline unsigned short f2bf(float f) {
  unsigned u = __float_as_uint(f);
  u += 0x7fffu + ((u >> 16) & 1u);
  return (unsigned short)(u >> 16);
}
__device__ inline unsigned pack2bf(float a, float b) {
  return (unsigned)f2bf(a) | ((unsigned)f2bf(b) << 16);
}
__device__ inline float bflo(unsigned u) { return __uint_as_float(u << 16); }
__device__ inline float bfhi(unsigned u) { return __uint_as_float(u & 0xffff0000u); }
// accumulate 4 bf16 (packed in uint2) into float4
__device__ inline void accb(float4& a, uint2 v) {
  a.x += bflo(v.x); a.y += bfhi(v.x);
  a.z += bflo(v.y); a.w += bfhi(v.y);
}

// ---------------- CSR build ----------------
__global__ void k_zero(int* p, int n) {
  int i = blockIdx.x * 256 + threadIdx.x;
  if (i < n) p[i] = 0;
}

__global__ void k_deg(const int* __restrict__ dst, int* __restrict__ deg) {
  int e = blockIdx.x * 256 + threadIdx.x;
  if (e < E_) atomicAdd(&deg[dst[e]], 1);
}

__global__ void k_scan(const int* __restrict__ deg, int* __restrict__ row_ptr,
                       float* __restrict__ inv_deg) {
  __shared__ int part[256];
  int tid = threadIdx.x;
  int base = tid * 40;
  int s = 0;
  for (int i = 0; i < 40; i++) { int idx = base + i; if (idx < N_) s += deg[idx]; }
  part[tid] = s;
  __syncthreads();
  if (tid == 0) {
    int run = 0;
    for (int i = 0; i < 256; i++) { int v = part[i]; part[i] = run; run += v; }
  }
  __syncthreads();
  int run = part[tid];
  for (int i = 0; i < 40; i++) {
    int idx = base + i;
    if (idx < N_) {
      row_ptr[idx] = run;
      int d = deg[idx];
      run += d;
      inv_deg[idx] = 1.0f / fmaxf((float)d, 1.0f);
    } else if (idx == N_) {
      row_ptr[N_] = run;
    }
  }
}

__global__ void k_fill(const int* __restrict__ src, const int* __restrict__ dst,
                       const int* __restrict__ row_ptr, int* __restrict__ cursor,
                       int* __restrict__ col) {
  int e = blockIdx.x * 256 + threadIdx.x;
  if (e < E_) {
    int d = dst[e];
    int p = atomicAdd(&cursor[d], 1);
    col[row_ptr[d] + p] = src[e];
  }
}

// ---------------- weight transposes ----------------
// sage2: Wt[w][k][jj], k in [0,128) (0:64 = W2l cols, 64:128 = W2r cols)
__global__ void k_prepw(const float* __restrict__ W2l, const float* __restrict__ W2r,
                        float* __restrict__ Wt) {
  int idx = blockIdx.x * 256 + threadIdx.x;   // 8192 total
  if (idx >= 4 * 128 * 16) return;
  int w = idx >> 11;
  int r = idx & 2047;
  int k = r >> 4;
  int jj = r & 15;
  int j = w * 16 + jj;
  float v = (k < 64) ? W2l[j * 64 + k] : W2r[j * 64 + (k - 64)];
  Wt[idx] = v;
}

// sage1: Wt1[w][k][jj], k in [0,32) (0:16 = W1l cols, 16:32 = W1r cols)
__global__ void k_prepw1(const float* __restrict__ W1l, const float* __restrict__ W1r,
                         float* __restrict__ Wt1) {
  int idx = blockIdx.x * 256 + threadIdx.x;   // 2048 total
  if (idx >= 4 * 32 * 16) return;
  int w = idx >> 9;
  int r = idx & 511;
  int k = r >> 4;
  int jj = r & 15;
  int j = w * 16 + jj;
  float v = (k < 16) ? W1l[j * 16 + k] : W1r[j * 16 + (k - 16)];
  Wt1[idx] = v;
}

// ---------------- SAGE layer 1, two-phase (no per-lane weights) ----------------
// Phase A: quad-node gather (lane = (eo edge-slot, f feature)), butterfly,
// agg+self -> LDS tile Z1[64][33] (fp32, stride 33 -> conflict-free Phase B).
// Phase B: lane = node, wave = j-quarter, wave-uniform scalar weight loads,
// LN cross-wave via LDS, bf16 uint4 stores. VGPR ~56 -> real 8 blocks/CU.
__launch_bounds__(256, 8)
__global__ void k_sage1t(const float* __restrict__ x, const int* __restrict__ row_ptr,
                         const int* __restrict__ col, const float* __restrict__ inv_deg,
                         const float* __restrict__ Wt1, const float* __restrict__ b1,
                         const float* __restrict__ g1, const float* __restrict__ be1,
                         unsigned short* __restrict__ h1, int bt0, int CH, int swz) {
  __shared__ float Z1[64 * 33];     // 8.4 KB
  __shared__ float red[2][4][64];   // 2 KB
  int i = blockIdx.x;
  int btl, chunk;
  if (swz) {  // pin all blocks of one bt to one XCD
    int xcd = i & 7; int j = i >> 3; int per = CH >> 3;
    btl = xcd * per + j / PB_; chunk = j % PB_;
  } else {
    btl = i / PB_; chunk = i % PB_;
  }
  int bt = bt0 + btl;
  size_t xbase = (size_t)bt * (N_ * F_);
  int tid = threadIdx.x;
  int w = __builtin_amdgcn_readfirstlane(tid >> 6);
  int lane = tid & 63;
  int n0 = chunk * 64;
  int f = lane & 15, eo = lane >> 4;

  // ---- Phase A ----
  for (int p = 0; p < 16; p += 4) {
    int mA = w * 16 + p;
    int nA = n0 + mA, nB = nA + 1, nC = nA + 2, nD = nA + 3;
    bool okA = nA < N_, okB = nB < N_, okC = nC < N_, okD = nD < N_;
    int s0A = 0, dA = 0, s0B = 0, dB = 0, s0C = 0, dC = 0, s0D = 0, dD = 0;
    float ivA = 0.f, ivB = 0.f, ivC = 0.f, ivD = 0.f;
    if (okA) { s0A = row_ptr[nA]; dA = row_ptr[nA + 1] - s0A; ivA = inv_deg[nA]; }
    if (okB) { s0B = row_ptr[nB]; dB = row_ptr[nB + 1] - s0B; ivB = inv_deg[nB]; }
    if (okC) { s0C = row_ptr[nC]; dC = row_ptr[nC + 1] - s0C; ivC = inv_deg[nC]; }
    if (okD) { s0D = row_ptr[nD]; dD = row_ptr[nD + 1] - s0D; ivD = inv_deg[nD]; }
    int colA = (lane < dA) ? col[s0A + lane] : 0;
    int colB = (lane < dB) ? col[s0B + lane] : 0;
    int colC = (lane < dC) ? col[s0C + lane] : 0;
    int colD = (lane < dD) ? col[s0D + lane] : 0;
    int dcA = dA > 64 ? 64 : dA, dcB = dB > 64 ? 64 : dB;
    int dcC = dC > 64 ? 64 : dC, dcD = dD > 64 ? 64 : dD;
    int mx = max(max(dcA, dcB), max(dcC, dcD));
    float aA = 0.f, aB = 0.f, aC = 0.f, aD = 0.f;
    int rounds = (mx + 3) >> 2;
    for (int r = 0; r < rounds; ++r) {
      int idx = eo + 4 * r;     // <= 63
      int sA = __shfl(colA, idx), sB = __shfl(colB, idx);
      int sC = __shfl(colC, idx), sD = __shfl(colD, idx);
      if (idx < dcA) aA += x[xbase + (size_t)sA * F_ + f];
      if (idx < dcB) aB += x[xbase + (size_t)sB * F_ + f];
      if (idx < dcC) aC += x[xbase + (size_t)sC * F_ + f];
      if (idx < dcD) aD += x[xbase + (size_t)sD * F_ + f];
    }
    if (dA > 64) for (int e = s0A + 64; e < s0A + dA; ++e) { if (eo == 0) aA += x[xbase + (size_t)col[e] * F_ + f]; }
    if (dB > 64) for (int e = s0B + 64; e < s0B + dB; ++e) { if (eo == 0) aB += x[xbase + (size_t)col[e] * F_ + f]; }
    if (dC > 64) for (int e = s0C + 64; e < s0C + dC; ++e) { if (eo == 0) aC += x[xbase + (size_t)col[e] * F_ + f]; }
    if (dD > 64) for (int e = s0D + 64; e < s0D + dD; ++e) { if (eo == 0) aD += x[xbase + (size_t)col[e] * F_ + f]; }
    aA += __shfl_xor(aA, 16); aA += __shfl_xor(aA, 32);
    aB += __shfl_xor(aB, 16); aB += __shfl_xor(aB, 32);
    aC += __shfl_xor(aC, 16); aC += __shfl_xor(aC, 32);
    aD += __shfl_xor(aD, 16); aD += __shfl_xor(aD, 32);
    float asel = (eo == 0) ? aA * ivA : (eo == 1) ? aB * ivB : (eo == 2) ? aC * ivC : aD * ivD;
    int nS = nA + eo;
    float xsel = (nS < N_) ? x[xbase + (size_t)nS * F_ + f] : 0.f;
    Z1[(mA + eo) * 33 + f] = asel;
    Z1[(mA + eo) * 33 + 16 + f] = xsel;
  }
  __syncthreads();

  // ---- Phase B: lane = node m; wave-uniform scalar weight loads ----
  int m = lane;
  const float* wp0 = Wt1 + w * 512;   // [32][16] slab for this j-quarter
  float acc[16];
#pragma unroll
  for (int jj = 0; jj < 16; ++jj) acc[jj] = b1[w * 16 + jj];
  const float* zrow = Z1 + m * 33;
#pragma unroll 4
  for (int k = 0; k < 32; ++k) {
    float z = zrow[k];
    const float* wp = wp0 + k * 16;
#pragma unroll
    for (int jj = 0; jj < 16; ++jj) acc[jj] = fmaf(z, wp[jj], acc[jj]);
  }

  // ---- LayerNorm across j (4 waves hold j-quarters) ----
  float s1 = 0.f;
#pragma unroll
  for (int jj = 0; jj < 16; ++jj) s1 += acc[jj];
  red[0][w][m] = s1;
  __syncthreads();
  float mu = (red[0][0][m] + red[0][1][m] + red[0][2][m] + red[0][3][m]) * (1.f / 64.f);
  float v = 0.f;
#pragma unroll
  for (int jj = 0; jj < 16; ++jj) { float d = acc[jj] - mu; v += d * d; }
  red[1][w][m] = v;
  __syncthreads();
  float var = (red[1][0][m] + red[1][1][m] + red[1][2][m] + red[1][3][m]) * (1.f / 64.f);
  float r = rsqrtf(var + EPS_);

  // ---- relu + bf16 pack + store (32B per lane, full-line tile coverage) ----
  if ((n0 + m) < N_) {
#pragma unroll
    for (int jj = 0; jj < 16; ++jj)
      acc[jj] = fmaxf((acc[jj] - mu) * r * g1[w * 16 + jj] + be1[w * 16 + jj], 0.f);
    uint4 pa, pb;
    pa.x = pack2bf(acc[0], acc[1]);  pa.y = pack2bf(acc[2], acc[3]);
    pa.z = pack2bf(acc[4], acc[5]);  pa.w = pack2bf(acc[6], acc[7]);
    pb.x = pack2bf(acc[8], acc[9]);  pb.y = pack2bf(acc[10], acc[11]);
    pb.z = pack2bf(acc[12], acc[13]); pb.w = pack2bf(acc[14], acc[15]);
    unsigned short* dst = h1 + ((size_t)btl * N_ + n0 + m) * HG_ + w * 16;
    *(uint4*)dst = pa;
    *(uint4*)(dst + 8) = pb;
  }
}

// ---------------- SAGE layer 2 (bf16 in), tiled; bf16 Z tile, 8 blocks/CU ----
__launch_bounds__(256, 8)
__global__ void k_sage2t(const unsigned short* __restrict__ h1, const int* __restrict__ row_ptr,
                         const int* __restrict__ col, const float* __restrict__ inv_deg,
                         const float* __restrict__ Wt, const float* __restrict__ b2,
                         const float* __restrict__ g2, const float* __restrict__ be2,
                         float* __restrict__ Hsum, int bt0, int CH, int swz) {
  __shared__ __align__(16) unsigned short Zb[64 * 132];   // 16.9 KB (bf16)
  __shared__ float red[2][4][64];
  __shared__ float sw[64];
  int i = blockIdx.x;
  int btl, chunk;
  if (swz) {
    int xcd = i & 7; int j = i >> 3; int per = CH >> 3;
    btl = xcd * per + j / PB_; chunk = j % PB_;
  } else {
    btl = i / PB_; chunk = i % PB_;
  }
  int bt = bt0 + btl;
  int b = bt / T_, t = bt % T_;
  size_t hbase = (size_t)btl * (N_ * HG_);
  const uint2* h4 = (const uint2*)(h1 + hbase);   // one row = 16 uint2 (64 bf16)
  int tid = threadIdx.x;
  int w = __builtin_amdgcn_readfirstlane(tid >> 6);
  int lane = tid & 63;
  int n0 = chunk * 64;
  int eo = lane >> 4, fq = lane & 15;

  // ---- Phase A: quads of nodes, 8B bf16x4 gathers ----
  for (int p = 0; p < 16; p += 4) {
    int mA = w * 16 + p;
    int nA = n0 + mA, nB = nA + 1, nC = nA + 2, nD = nA + 3;
    bool okA = nA < N_, okB = nB < N_, okC = nC < N_, okD = nD < N_;
    int s0A = 0, dA = 0, s0B = 0, dB = 0, s0C = 0, dC = 0, s0D = 0, dD = 0;
    float ivA = 0.f, ivB = 0.f, ivC = 0.f, ivD = 0.f;
    if (okA) { s0A = row_ptr[nA]; dA = row_ptr[nA + 1] - s0A; ivA = inv_deg[nA]; }
    if (okB) { s0B = row_ptr[nB]; dB = row_ptr[nB + 1] - s0B; ivB = inv_deg[nB]; }
    if (okC) { s0C = row_ptr[nC]; dC = row_ptr[nC + 1] - s0C; ivC = inv_deg[nC]; }
    if (okD) { s0D = row_ptr[nD]; dD = row_ptr[nD + 1] - s0D; ivD = inv_deg[nD]; }
    int colA = (lane < dA) ? col[s0A + lane] : 0;
    int colB = (lane < dB) ? col[s0B + lane] : 0;
    int colC = (lane < dC) ? col[s0C + lane] : 0;
    int colD = (lane < dD) ? col[s0D + lane] : 0;
    int dcA = dA > 64 ? 64 : dA, dcB = dB > 64 ? 64 : dB;
    int dcC = dC > 64 ? 64 : dC, dcD = dD > 64 ? 64 : dD;
    int mx = max(max(dcA, dcB), max(dcC, dcD));
    float4 aA = {0, 0, 0, 0}, aB = {0, 0, 0, 0}, aC = {0, 0, 0, 0}, aD = {0, 0, 0, 0};
    int rounds = (mx + 3) >> 2;
    for (int r = 0; r < rounds; ++r) {
      int idx = eo + 4 * r;    // <= 63
      int sA = __shfl(colA, idx), sB = __shfl(colB, idx);
      int sC = __shfl(colC, idx), sD = __shfl(colD, idx);
      if (idx < dcA) accb(aA, h4[(size_t)sA * 16 + fq]);
      if (idx < dcB) accb(aB, h4[(size_t)sB * 16 + fq]);
      if (idx < dcC) accb(aC, h4[(size_t)sC * 16 + fq]);
      if (idx < dcD) accb(aD, h4[(size_t)sD * 16 + fq]);
    }
    if (dA > 64) for (int e = s0A + 64; e < s0A + dA; ++e) { if (eo == 0) accb(aA, h4[(size_t)col[e] * 16 + fq]); }
    if (dB > 64) for (int e = s0B + 64; e < s0B + dB; ++e) { if (eo == 0) accb(aB, h4[(size_t)col[e] * 16 + fq]); }
    if (dC > 64) for (int e = s0C + 64; e < s0C + dC; ++e) { if (eo == 0) accb(aC, h4[(size_t)col[e] * 16 + fq]); }
    if (dD > 64) for (int e = s0D + 64; e < s0D + dD; ++e) { if (eo == 0) accb(aD, h4[(size_t)col[e] * 16 + fq]); }
    float4 tA = shfl_xor4(aA, 16); aA.x += tA.x; aA.y += tA.y; aA.z += tA.z; aA.w += tA.w;
    tA = shfl_xor4(aA, 32); aA.x += tA.x; aA.y += tA.y; aA.z += tA.z; aA.w += tA.w;
    float4 tB = shfl_xor4(aB, 16); aB.x += tB.x; aB.y += tB.y; aB.z += tB.z; aB.w += tB.w;
    tB = shfl_xor4(aB, 32); aB.x += tB.x; aB.y += tB.y; aB.z += tB.z; aB.w += tB.w;
    float4 tC = shfl_xor4(aC, 16); aC.x += tC.x; aC.y += tC.y; aC.z += tC.z; aC.w += tC.w;
    tC = shfl_xor4(aC, 32); aC.x += tC.x; aC.y += tC.y; aC.z += tC.z; aC.w += tC.w;
    float4 tD = shfl_xor4(aD, 16); aD.x += tD.x; aD.y += tD.y; aD.z += tD.z; aD.w += tD.w;
    tD = shfl_xor4(aD, 32); aD.x += tD.x; aD.y += tD.y; aD.z += tD.z; aD.w += tD.w;
    float iv = (eo == 0) ? ivA : (eo == 1) ? ivB : (eo == 2) ? ivC : ivD;
    float4 agg = (eo == 0) ? aA : (eo == 1) ? aB : (eo == 2) ? aC : aD;
    agg.x *= iv; agg.y *= iv; agg.z *= iv; agg.w *= iv;
    uint2 ap;
    ap.x = pack2bf(agg.x, agg.y);
    ap.y = pack2bf(agg.z, agg.w);
    *(uint2*)&Zb[(mA + eo) * 132 + fq * 4] = ap;
    int nS = nA + eo;
    uint2 sv = {0, 0};
    if (nS < N_) sv = h4[(size_t)nS * 16 + fq];
    *(uint2*)&Zb[(mA + eo) * 132 + 64 + fq * 4] = sv;
  }
  __syncthreads();

  // ---- Phase B: lane = node m; wave-uniform scalar weight loads ----
  int m = lane;
  const float* wp0 = Wt + w * 2048;
  float acc[16];
#pragma unroll
  for (int jj = 0; jj < 16; ++jj) acc[jj] = b2[w * 16 + jj];
  const unsigned short* zrow = Zb + m * 132;
  for (int kg = 0; kg < 32; ++kg) {
    uint2 zp = *(const uint2*)(zrow + kg * 4);
    float4 z;
    z.x = bflo(zp.x); z.y = bfhi(zp.x);
    z.z = bflo(zp.y); z.w = bfhi(zp.y);
    const float* wp = wp0 + kg * 64;
#pragma unroll
    for (int jj = 0; jj < 16; ++jj) {
      acc[jj] = fmaf(z.x, wp[jj], acc[jj]);
      acc[jj] = fmaf(z.y, wp[16 + jj], acc[jj]);
      acc[jj] = fmaf(z.z, wp[32 + jj], acc[jj]);
      acc[jj] = fmaf(z.w, wp[48 + jj], acc[jj]);
    }
  }

  // ---- LayerNorm across j (4 waves hold j-quarters) ----
  float s1 = 0.f;
#pragma unroll
  for (int jj = 0; jj < 16; ++jj) s1 += acc[jj];
  red[0][w][m] = s1;
  __syncthreads();
  float mu = (red[0][0][m] + red[0][1][m] + red[0][2][m] + red[0][3][m]) * (1.f / 64.f);
  float v = 0.f;
#pragma unroll
  for (int jj = 0; jj < 16; ++jj) { float d = acc[jj] - mu; v += d * d; }
  red[1][w][m] = v;
  __syncthreads();
  float var = (red[1][0][m] + red[1][1][m] + red[1][2][m] + red[1][3][m]) * (1.f / 64.f);
  float r = rsqrtf(var + EPS_);

  // ---- relu + mean-over-N partial ----
  bool okm = (n0 + m) < N_;
#pragma unroll
  for (int jj = 0; jj < 16; ++jj) {
    float hv = fmaxf((acc[jj] - mu) * r * g2[w * 16 + jj] + be2[w * 16 + jj], 0.f);
    acc[jj] = okm ? hv : 0.f;
  }
#pragma unroll
  for (int m2 = 1; m2 < 64; m2 <<= 1) {
#pragma unroll
    for (int jj = 0; jj < 16; ++jj) acc[jj] += __shfl_xor(acc[jj], m2);
  }
  if (lane == 0) {
#pragma unroll
    for (int jj = 0; jj < 16; ++jj) sw[w * 16 + jj] = acc[jj];
  }
  __syncthreads();
  if (w == 0) atomicAdd(&Hsum[(t * B_ + b) * HG_ + lane], sw[lane]);
}

// ---------------- GRU input precompute: GI[t][b][384] ----------------
__global__ void k_gi(const float* __restrict__ Hsum, const float* __restrict__ W_ih,
                     const float* __restrict__ b_ih, float* __restrict__ GI) {
  __shared__ float xv[64];
  int tb = blockIdx.x;
  int tid = threadIdx.x;
  if (tid < 64) xv[tid] = Hsum[tb * 64 + tid] * (1.0f / (float)N_);
  __syncthreads();
  float g = b_ih[tid];
  const float4* W4 = (const float4*)(W_ih + tid * 64);
  const float4* x4 = (const float4*)xv;
#pragma unroll
  for (int q = 0; q < 16; q++) {
    float4 w = W4[q], xq = x4[q];
    g = fmaf(xq.x, w.x, g); g = fmaf(xq.y, w.y, g);
    g = fmaf(xq.z, w.z, g); g = fmaf(xq.w, w.w, g);
  }
  GI[tb * 384 + tid] = g;
}

// ---------------- sequential GRU + head; one block per batch ----------------
__global__ void k_gru(const float* __restrict__ GI, const float* __restrict__ W_hh,
                      const float* __restrict__ b_hh, const float* __restrict__ Wh,
                      const float* __restrict__ bh, float* __restrict__ out) {
  __shared__ float hL[128];
  __shared__ float ghL[384];
  __shared__ float red[128];
  int b = blockIdx.x, tid = threadIdx.x;
  if (tid < 128) hL[tid] = 0.f;
  float bhh = b_hh[tid];
  const float4* W4 = (const float4*)(W_hh + tid * 128);
  for (int t = 0; t < T_; ++t) {
    __syncthreads();
    float g = bhh;
    const float4* h4 = (const float4*)hL;
#pragma unroll
    for (int q = 0; q < 32; q++) {
      float4 w = W4[q], hv = h4[q];
      g = fmaf(hv.x, w.x, g); g = fmaf(hv.y, w.y, g);
      g = fmaf(hv.z, w.z, g); g = fmaf(hv.w, w.w, g);
    }
    ghL[tid] = g;
    __syncthreads();
    float hnew = 0.f;
    if (tid < 128) {
      const float* gi = GI + (t * B_ + b) * 384;
      float rr = 1.f / (1.f + expf(-(gi[tid] + ghL[tid])));
      float zz = 1.f / (1.f + expf(-(gi[128 + tid] + ghL[128 + tid])));
      float nn = tanhf(gi[256 + tid] + rr * ghL[256 + tid]);
      hnew = (1.f - zz) * nn + zz * hL[tid];
    }
    __syncthreads();
    if (tid < 128) hL[tid] = hnew;
  }
  __syncthreads();
  if (tid < 128) red[tid] = hL[tid] * Wh[tid];
  __syncthreads();
  if (tid == 0) {
    float s = bh[0];
    for (int k = 0; k < 128; k++) s += red[k];
    out[b] = s;
  }
}

extern "C" void kernel_launch(void* const* d_in, const int* in_sizes, int n_in,
                              void* d_out, int out_size, void* d_ws, size_t ws_size,
                              hipStream_t stream) {
  const float* x    = (const float*)d_in[0];
  const int*   ei   = (const int*)d_in[1];
  const float* W1l  = (const float*)d_in[2];
  const float* b1   = (const float*)d_in[3];
  const float* W1r  = (const float*)d_in[4];
  const float* g1   = (const float*)d_in[5];
  const float* be1  = (const float*)d_in[6];
  const float* W2l  = (const float*)d_in[7];
  const float* b2   = (const float*)d_in[8];
  const float* W2r  = (const float*)d_in[9];
  const float* g2   = (const float*)d_in[10];
  const float* be2  = (const float*)d_in[11];
  const float* W_ih = (const float*)d_in[12];
  const float* W_hh = (const float*)d_in[13];
  const float* b_ih = (const float*)d_in[14];
  const float* b_hh = (const float*)d_in[15];
  const float* Wh   = (const float*)d_in[16];
  const float* bh   = (const float*)d_in[17];
  float* out = (float*)d_out;

  char* ws = (char*)d_ws;
  size_t off = 0;
  auto alloc = [&](size_t bytes) { void* p = ws + off; off += (bytes + 255) & ~(size_t)255; return p; };
  int*   deg     = (int*)alloc((size_t)N_ * 4);
  int*   row_ptr = (int*)alloc((size_t)(N_ + 1) * 4);
  int*   cursor  = (int*)alloc((size_t)N_ * 4);
  int*   col     = (int*)alloc((size_t)E_ * 4);
  float* ivd     = (float*)alloc((size_t)N_ * 4);
  float* Hsum    = (float*)alloc((size_t)BT_ * HG_ * 4);
  float* GI      = (float*)alloc((size_t)BT_ * 384 * 4);
  float* Wt      = (float*)alloc((size_t)4 * 128 * 16 * 4);
  float* Wt1     = (float*)alloc((size_t)4 * 32 * 16 * 4);
  size_t fixed = off;
  unsigned short* h1 = (unsigned short*)(ws + off);

  size_t cap = (ws_size > fixed) ? (ws_size - fixed) : 0;
  int CH = (int)(cap / ((size_t)N_ * HG_ * 2));   // bf16 h1
  if (CH > 64) CH = 64;    // keep chunk working set inside the 256MB L3
  if (CH >= 8) CH &= ~7;   // multiple of 8 for XCD swizzle
  if (CH < 1) CH = 1;

  int zn = (int)(fixed / 4);
  k_zero<<<(zn + 255) / 256, 256, 0, stream>>>((int*)ws, zn);

  const int* srcp = ei;
  const int* dstp = ei + E_;
  k_deg<<<(E_ + 255) / 256, 256, 0, stream>>>(dstp, deg);
  k_scan<<<1, 256, 0, stream>>>(deg, row_ptr, ivd);
  k_fill<<<(E_ + 255) / 256, 256, 0, stream>>>(srcp, dstp, row_ptr, cursor, col);
  k_prepw<<<32, 256, 0, stream>>>(W2l, W2r, Wt);
  k_prepw1<<<8, 256, 0, stream>>>(W1l, W1r, Wt1);

  for (int bt0 = 0; bt0 < BT_; bt0 += CH) {
    int c = BT_ - bt0 < CH ? BT_ - bt0 : CH;
    int swz = (c % 8 == 0) ? 1 : 0;
    k_sage1t<<<c * PB_, 256, 0, stream>>>(x, row_ptr, col, ivd, Wt1, b1, g1, be1,
                                          h1, bt0, c, swz);
    k_sage2t<<<c * PB_, 256, 0, stream>>>(h1, row_ptr, col, ivd, Wt, b2, g2, be2,
                                          Hsum, bt0, c, swz);
  }
  k_gi<<<BT_, 384, 0, stream>>>(Hsum, W_ih, b_ih, GI);
  k_gru<<<B_, 384, 0, stream>>>(GI, W_hh, b_hh, Wh, bh, out);
}